// Round 18
// baseline (692.905 us; speedup 1.0000x reference)
//
#include <hip/hip_runtime.h>

#define SCAN_B 1024
#define NGRAPH 128
typedef unsigned short u16;
typedef unsigned int u32;
typedef u32 u32x2 __attribute__((ext_vector_type(2)));
typedef u32 u32x4 __attribute__((ext_vector_type(4)));
typedef float fx4 __attribute__((ext_vector_type(4)));
typedef int ix2 __attribute__((ext_vector_type(2)));
typedef _Float16 f16;
typedef _Float16 f16x8 __attribute__((ext_vector_type(8)));
typedef float f32x4 __attribute__((ext_vector_type(4)));

__device__ __forceinline__ u16 f2h(float f) {
  f16 h = (f16)f;
  return __builtin_bit_cast(u16, h);
}
__device__ __forceinline__ float h2f(u16 u) {
  return (float)__builtin_bit_cast(f16, u);
}
__device__ __forceinline__ float hlo(u32 w) { return h2f((u16)(w & 0xffffu)); }
__device__ __forceinline__ float hhi(u32 w) { return h2f((u16)(w >> 16)); }

// compute BN scale/shift for 4 channels from raw stats
__device__ __forceinline__ void bn4(const float* __restrict__ stat,
                                    const float* __restrict__ gamma,
                                    const float* __restrict__ beta,
                                    float invN, int c4,
                                    float4& sc4, float4& sh4)
{
  float4 s1 = *(const float4*)&stat[c4];
  float4 s2 = *(const float4*)&stat[64 + c4];
  float4 g4 = *(const float4*)&gamma[c4];
  float4 b4 = *(const float4*)&beta[c4];
#define BN1(k)                                                        \
  { float mu = s1.k * invN;                                           \
    float var = fmaxf(s2.k * invN - mu * mu, 0.f);                    \
    sc4.k = g4.k * rsqrtf(var + 1e-5f);                               \
    sh4.k = b4.k - mu * sc4.k; }
  BN1(x) BN1(y) BN1(z) BN1(w)
#undef BN1
}

// ---------------- node encoder: h = x @ W(32x64) + b  -> f16 ---------------
__global__ __launch_bounds__(256) void node_enc_kernel(
    const float* __restrict__ x, const float* __restrict__ W,
    const float* __restrict__ b, u16* __restrict__ zh, int N)
{
  int lane = threadIdx.x & 63;
  int wave = (blockIdx.x * blockDim.x + threadIdx.x) >> 6;
  int nw = (gridDim.x * blockDim.x) >> 6;
  float wcol[32];
#pragma unroll
  for (int k = 0; k < 32; ++k) wcol[k] = W[k * 64 + lane];
  float bb = b[lane];
  for (int n = wave; n < N; n += nw) {
    const fx4* xr = (const fx4*)(x + (size_t)n * 32);
    float acc = bb;
#pragma unroll
    for (int c = 0; c < 8; ++c) {
      fx4 v = __builtin_nontemporal_load(&xr[c]);
      acc = fmaf(v[0], wcol[4 * c + 0], acc);
      acc = fmaf(v[1], wcol[4 * c + 1], acc);
      acc = fmaf(v[2], wcol[4 * c + 2], acc);
      acc = fmaf(v[3], wcol[4 * c + 3], acc);
    }
    zh[(size_t)n * 64 + lane] = f2h(acc);
  }
}

// ---------------- CSR build ------------------------------------------------
__global__ __launch_bounds__(256) void count_pos_kernel(
    const int* __restrict__ dst, int* __restrict__ deg,
    int* __restrict__ pos, int E)
{
  int e = blockIdx.x * blockDim.x + threadIdx.x;
  if (e < E) pos[e] = atomicAdd(&deg[dst[e]], 1);
}

__global__ __launch_bounds__(SCAN_B) void scan1_kernel(
    const int* __restrict__ deg, int* __restrict__ rowp,
    int* __restrict__ bsum, int N)
{
  __shared__ int s[SCAN_B];
  int tid = threadIdx.x;
  int i = blockIdx.x * SCAN_B + tid;
  int v = (i < N) ? deg[i] : 0;
  s[tid] = v;
  __syncthreads();
  for (int off = 1; off < SCAN_B; off <<= 1) {
    int t = (tid >= off) ? s[tid - off] : 0;
    __syncthreads();
    s[tid] += t;
    __syncthreads();
  }
  if (i < N) rowp[i] = s[tid] - v;          // exclusive
  if (tid == SCAN_B - 1) bsum[blockIdx.x] = s[tid];
}

__global__ __launch_bounds__(128) void scan2_kernel(int* __restrict__ bsum, int NB)
{
  __shared__ int s[128];
  int tid = threadIdx.x;
  int v = (tid < NB) ? bsum[tid] : 0;
  s[tid] = v;
  __syncthreads();
  for (int off = 1; off < 128; off <<= 1) {
    int t = (tid >= off) ? s[tid - off] : 0;
    __syncthreads();
    s[tid] += t;
    __syncthreads();
  }
  if (tid < NB) bsum[tid] = s[tid] - v;     // exclusive block offsets
}

__global__ __launch_bounds__(SCAN_B) void scan3_kernel(
    int* __restrict__ rowp, const int* __restrict__ bsum, int N, int E)
{
  int i = blockIdx.x * SCAN_B + threadIdx.x;
  if (i < N) rowp[i] += bsum[blockIdx.x];
  if (i == 0) rowp[N] = E;
}

// fallback: scattered (src,eid) pairs into CSR slots
__global__ __launch_bounds__(256) void scatter_pairs_kernel(
    const int* __restrict__ dst, const int* __restrict__ src,
    const int* __restrict__ pos, const int* __restrict__ rowp,
    ix2* __restrict__ pairs, int E)
{
  int e = blockIdx.x * blockDim.x + threadIdx.x;
  if (e >= E) return;
  int p = rowp[dst[e]] + pos[e];
  ix2 v; v[0] = src[e]; v[1] = e;
  pairs[p] = v;
}

// one-time: eWt[d][k] f16, K padded 16->32 with zeros (for MFMA B-fragments)
__global__ __launch_bounds__(256) void prep_ew_kernel(
    const float* __restrict__ eW, u16* __restrict__ eWt)
{
  int idx = blockIdx.x * 256 + threadIdx.x;   // 64*32 = 2048
  if (idx >= 2048) return;
  int d = idx >> 5, k = idx & 31;
  eWt[idx] = (k < 16) ? f2h(eW[k * 64 + d]) : (u16)0;
}

// MFMA encode + fused pair-scatter.
// e_nat[e] = attr[e] @ eW + eb (f16, natural order, coalesced);
// pairs[rowp[dst[e]]+pos[e]] = (src[e], e) (scattered 8B, latency-hidden).
__global__ __launch_bounds__(256) void encode_mfma_kernel(
    const float* __restrict__ attr, const u16* __restrict__ eWt,
    const float* __restrict__ eb_, u16* __restrict__ e_nat,
    const int* __restrict__ dst, const int* __restrict__ src,
    const int* __restrict__ pos, const int* __restrict__ rowp,
    ix2* __restrict__ pairs, int E)
{
  __shared__ __align__(16) u16 ylds[4][16][72];
  int lane = threadIdx.x & 63;
  int l15 = lane & 15, lg = lane >> 4;
  int w = threadIdx.x >> 6;
  int wave = (blockIdx.x * blockDim.x + threadIdx.x) >> 6;
  int nw = (gridDim.x * blockDim.x) >> 6;

  f16x8 wf[4];
#pragma unroll
  for (int nt = 0; nt < 4; ++nt)
    wf[nt] = *(const f16x8*)&eWt[(nt * 16 + l15) * 32 + lg * 8];
  float bv[4];
#pragma unroll
  for (int nt = 0; nt < 4; ++nt) bv[nt] = eb_[nt * 16 + l15];

  int ntiles = (E + 15) >> 4;
  for (int tile = wave; tile < ntiles; tile += nw) {
    int e0 = tile << 4;
    // fused pair scatter (quarter 0 handles this tile's 16 edges)
    if (lg == 0) {
      int e = e0 + l15;
      if (e < E) {
        int p = rowp[dst[e]] + pos[e];
        ix2 v; v[0] = src[e]; v[1] = e;
        pairs[p] = v;
      }
    }
    f16x8 af = (f16x8){0, 0, 0, 0, 0, 0, 0, 0};
    if (lg < 2) {
      int e = e0 + l15; if (e >= E) e = E - 1;
      const fx4* ar = (const fx4*)(attr + (size_t)e * 16 + lg * 8);
      fx4 v0 = __builtin_nontemporal_load(ar);
      fx4 v1 = __builtin_nontemporal_load(ar + 1);
      af[0] = (f16)v0[0]; af[1] = (f16)v0[1];
      af[2] = (f16)v0[2]; af[3] = (f16)v0[3];
      af[4] = (f16)v1[0]; af[5] = (f16)v1[1];
      af[6] = (f16)v1[2]; af[7] = (f16)v1[3];
    }
    f32x4 c[4];
#pragma unroll
    for (int nt = 0; nt < 4; ++nt) {
      c[nt] = (f32x4){0.f, 0.f, 0.f, 0.f};
      c[nt] = __builtin_amdgcn_mfma_f32_16x16x32_f16(af, wf[nt], c[nt], 0, 0, 0);
    }
    // transpose through per-wave LDS (same-wave RAW: lgkmcnt-ordered)
#pragma unroll
    for (int nt = 0; nt < 4; ++nt)
#pragma unroll
      for (int r = 0; r < 4; ++r)
        ylds[w][lg * 4 + r][nt * 16 + l15] = f2h(c[nt][r] + bv[nt]);
    int e = e0 + l15;
    if (e < E) {
      u32x4 lo = *(const u32x4*)&ylds[w][l15][lg * 16];
      u32x4 hi = *(const u32x4*)&ylds[w][l15][lg * 16 + 8];
      u32x4* orow = (u32x4*)(e_nat + (size_t)e * 64 + lg * 16);
      orow[0] = lo;
      orow[1] = hi;
    }
  }
}

// ------- one-time: transpose+convert MLP weights to f16 [layer][2][d][k] ---
__global__ __launch_bounds__(256) void prep_weights_kernel(
    const float* __restrict__ mlp1_W, const float* __restrict__ mlp2_W,
    u16* __restrict__ Wt)
{
  int idx = blockIdx.x * 256 + threadIdx.x;     // 4*2*64*64 = 32768
  if (idx >= 32768) return;
  int layer = idx >> 13;
  int which = (idx >> 12) & 1;
  int d = (idx >> 6) & 63;
  int k = idx & 63;
  const float* W = which ? mlp2_W : mlp1_W;
  Wt[idx] = f2h(W[layer * 4096 + k * 64 + d]);
}

// ---------------- gather: pairs (src,eid) + natural-order e_nat ------------
// gh[i] = hval(zh[i]) + sum_{e: dst=i} relu(hval(zh[src_e]) + e_nat[eid])
__global__ __launch_bounds__(256, 4) void gather_kernel(
    const u16* __restrict__ zh, const float* __restrict__ stat_rd,
    const float* __restrict__ gamma, const float* __restrict__ beta,
    float invN, float* __restrict__ stat_wr,
    const u16* __restrict__ e_nat, const ix2* __restrict__ pairs,
    const int* __restrict__ rowp, u16* __restrict__ gh, int N)
{
  if (blockIdx.x == 0 && threadIdx.x < 128) stat_wr[threadIdx.x] = 0.f;

  int lane = threadIdx.x & 63;
  int c = lane & 15, q = lane >> 4;           // channels 4c..4c+3, quarter q
  int wave = (blockIdx.x * blockDim.x + threadIdx.x) >> 6;
  int nw = (gridDim.x * blockDim.x) >> 6;

  const bool ubn = stat_rd != nullptr;
  float4 sc4 = make_float4(1.f, 1.f, 1.f, 1.f);
  float4 sh4 = make_float4(0.f, 0.f, 0.f, 0.f);
  if (ubn) bn4(stat_rd, gamma, beta, invN, 4 * c, sc4, sh4);

  auto hval4 = [&](u32x2 z, float& h0, float& h1, float& h2, float& h3) {
    h0 = hlo(z[0]); h1 = hhi(z[0]); h2 = hlo(z[1]); h3 = hhi(z[1]);
    if (ubn) {
      h0 = fmaxf(fmaf(h0, sc4.x, sh4.x), 0.f);
      h1 = fmaxf(fmaf(h1, sc4.y, sh4.y), 0.f);
      h2 = fmaxf(fmaf(h2, sc4.z, sh4.z), 0.f);
      h3 = fmaxf(fmaf(h3, sc4.w, sh4.w), 0.f);
    }
  };
  auto body = [&](u32x2 z, u32x2 e,
                  float& A0, float& A1, float& A2, float& A3) {
    float h0, h1, h2, h3;
    hval4(z, h0, h1, h2, h3);
    A0 += fmaxf(h0 + hlo(e[0]), 0.f);
    A1 += fmaxf(h1 + hhi(e[0]), 0.f);
    A2 += fmaxf(h2 + hlo(e[1]), 0.f);
    A3 += fmaxf(h3 + hhi(e[1]), 0.f);
  };

  for (int node = wave; node < N; node += nw) {
    const int j0 = rowp[node], j1 = rowp[node + 1];
    float acc0 = 0.f, acc1 = 0.f, acc2 = 0.f, acc3 = 0.f;

    for (int base = j0; base < j1; base += 64) {
      int nb = j1 - base; if (nb > 64) nb = 64;
      ix2 iv = {0, 0};
      if (lane < nb) iv = pairs[base + lane];
      int sv = iv[0], dv = iv[1];
      int ng = nb >> 2;
      int t = 0;
      for (; t + 4 <= ng; t += 4) {           // 16 edges: loads up front
        int s0 = __shfl(sv, 4 * t + q, 64);
        int s1 = __shfl(sv, 4 * t + 4 + q, 64);
        int s2 = __shfl(sv, 4 * t + 8 + q, 64);
        int s3 = __shfl(sv, 4 * t + 12 + q, 64);
        int d0 = __shfl(dv, 4 * t + q, 64);
        int d1 = __shfl(dv, 4 * t + 4 + q, 64);
        int d2 = __shfl(dv, 4 * t + 8 + q, 64);
        int d3 = __shfl(dv, 4 * t + 12 + q, 64);
        u32x2 z0 = *(const u32x2*)(zh + (size_t)s0 * 64 + 4 * c);
        u32x2 z1 = *(const u32x2*)(zh + (size_t)s1 * 64 + 4 * c);
        u32x2 z2 = *(const u32x2*)(zh + (size_t)s2 * 64 + 4 * c);
        u32x2 z3 = *(const u32x2*)(zh + (size_t)s3 * 64 + 4 * c);
        u32x2 e0 = *(const u32x2*)(e_nat + (size_t)d0 * 64 + 4 * c);
        u32x2 e1 = *(const u32x2*)(e_nat + (size_t)d1 * 64 + 4 * c);
        u32x2 e2 = *(const u32x2*)(e_nat + (size_t)d2 * 64 + 4 * c);
        u32x2 e3 = *(const u32x2*)(e_nat + (size_t)d3 * 64 + 4 * c);
        body(z0, e0, acc0, acc1, acc2, acc3);
        body(z1, e1, acc0, acc1, acc2, acc3);
        body(z2, e2, acc0, acc1, acc2, acc3);
        body(z3, e3, acc0, acc1, acc2, acc3);
      }
      for (; t < ng; ++t) {
        int s0 = __shfl(sv, 4 * t + q, 64);
        int d0 = __shfl(dv, 4 * t + q, 64);
        u32x2 z0 = *(const u32x2*)(zh + (size_t)s0 * 64 + 4 * c);
        u32x2 e0 = *(const u32x2*)(e_nat + (size_t)d0 * 64 + 4 * c);
        body(z0, e0, acc0, acc1, acc2, acc3);
      }
      int tail = nb & 3;
      if (tail) {
        int idx = 4 * ng + (q < tail ? q : 0);  // clamp to valid slot
        int s0 = __shfl(sv, idx, 64);
        int d0 = __shfl(dv, idx, 64);
        u32x2 z0 = *(const u32x2*)(zh + (size_t)s0 * 64 + 4 * c);
        u32x2 e0 = *(const u32x2*)(e_nat + (size_t)d0 * 64 + 4 * c);
        float h0, h1, h2, h3;
        hval4(z0, h0, h1, h2, h3);
        float wmask = (q < tail) ? 1.f : 0.f;
        acc0 += wmask * fmaxf(h0 + hlo(e0[0]), 0.f);
        acc1 += wmask * fmaxf(h1 + hhi(e0[0]), 0.f);
        acc2 += wmask * fmaxf(h2 + hlo(e0[1]), 0.f);
        acc3 += wmask * fmaxf(h3 + hhi(e0[1]), 0.f);
      }
    }
    acc0 += __shfl_xor(acc0, 16, 64); acc0 += __shfl_xor(acc0, 32, 64);
    acc1 += __shfl_xor(acc1, 16, 64); acc1 += __shfl_xor(acc1, 32, 64);
    acc2 += __shfl_xor(acc2, 16, 64); acc2 += __shfl_xor(acc2, 32, 64);
    acc3 += __shfl_xor(acc3, 16, 64); acc3 += __shfl_xor(acc3, 32, 64);
    if (q == 0) {
      u32x2 zn = *(const u32x2*)(zh + (size_t)node * 64 + 4 * c);
      float h0, h1, h2, h3;
      hval4(zn, h0, h1, h2, h3);
      acc0 += h0; acc1 += h1; acc2 += h2; acc3 += h3;
      u32x2 o;
      o[0] = (u32)f2h(acc0) | ((u32)f2h(acc1) << 16);
      o[1] = (u32)f2h(acc2) | ((u32)f2h(acc3) << 16);
      *(u32x2*)(gh + (size_t)node * 64 + 4 * c) = o;
    }
  }
}

// ---------------- fallback gather (pairs + f32 attr recompute) -------------
__global__ __launch_bounds__(256) void gather_fallback_kernel(
    const u16* __restrict__ zh, const float* __restrict__ stat_rd,
    const float* __restrict__ gamma, const float* __restrict__ beta,
    float invN, float* __restrict__ stat_wr,
    const ix2* __restrict__ pairs, const int* __restrict__ rowp,
    const float* __restrict__ attr, const float* __restrict__ eW,
    const float* __restrict__ eb_, u16* __restrict__ gh, int N)
{
  if (blockIdx.x == 0 && threadIdx.x < 128) stat_wr[threadIdx.x] = 0.f;
  int lane = threadIdx.x & 63;
  int node = (blockIdx.x * blockDim.x + threadIdx.x) >> 6;
  if (node >= N) return;
  const bool ubn = stat_rd != nullptr;
  float sc = 1.f, sh = 0.f;
  if (ubn) {
    float mu = stat_rd[lane] * invN;
    float var = fmaxf(stat_rd[64 + lane] * invN - mu * mu, 0.f);
    sc = gamma[lane] * rsqrtf(var + 1e-5f);
    sh = beta[lane] - mu * sc;
  }
  auto hval = [&](float zz) -> float {
    float v = fmaf(zz, sc, sh);
    return ubn ? fmaxf(v, 0.f) : v;
  };
  float wcol[16];
#pragma unroll
  for (int k = 0; k < 16; ++k) wcol[k] = eW[k * 64 + lane];
  float eb = eb_[lane];
  const int j0 = rowp[node], j1 = rowp[node + 1];
  float acc = hval(h2f(zh[(size_t)node * 64 + lane]));
  for (int j = j0; j < j1; ++j) {
    ix2 pr = pairs[j];
    int s = pr[0], eid = pr[1];
    const float4* ar = (const float4*)(attr + (size_t)eid * 16);
    float4 a0 = ar[0], a1 = ar[1], a2 = ar[2], a3 = ar[3];
    float m = eb;
    m = fmaf(a0.x, wcol[0], m);  m = fmaf(a0.y, wcol[1], m);
    m = fmaf(a0.z, wcol[2], m);  m = fmaf(a0.w, wcol[3], m);
    m = fmaf(a1.x, wcol[4], m);  m = fmaf(a1.y, wcol[5], m);
    m = fmaf(a1.z, wcol[6], m);  m = fmaf(a1.w, wcol[7], m);
    m = fmaf(a2.x, wcol[8], m);  m = fmaf(a2.y, wcol[9], m);
    m = fmaf(a2.z, wcol[10], m); m = fmaf(a2.w, wcol[11], m);
    m = fmaf(a3.x, wcol[12], m); m = fmaf(a3.y, wcol[13], m);
    m = fmaf(a3.z, wcol[14], m); m = fmaf(a3.w, wcol[15], m);
    acc += fmaxf(hval(h2f(zh[(size_t)s * 64 + lane])) + m, 0.f);
  }
  gh[(size_t)node * 64 + lane] = f2h(acc);
}

// ---------------- MFMA fused MLP + BN stats (32 rows/wave) -----------------
__global__ __launch_bounds__(256) void mlp_mfma_kernel(
    const u16* __restrict__ gh, u16* __restrict__ zh,
    const u16* __restrict__ W1t, const u16* __restrict__ W2t,
    const float* __restrict__ b1, const float* __restrict__ b2,
    float* __restrict__ stat, int N)
{
  __shared__ __align__(16) u16 ylds[4][16][72];
  __shared__ float sstat[128];
  int tid = threadIdx.x, lane = tid & 63, w = tid >> 6;
  int l15 = lane & 15, lg = lane >> 4;
  int row_base = (blockIdx.x * 4 + w) * 32;

  if (tid < 128) sstat[tid] = 0.f;
  __syncthreads();

  f16x8 w1f[2][4], w2f[2][4];
#pragma unroll
  for (int ks = 0; ks < 2; ++ks)
#pragma unroll
    for (int nt = 0; nt < 4; ++nt) {
      int off = (nt * 16 + l15) * 64 + ks * 32 + lg * 8;
      w1f[ks][nt] = *(const f16x8*)&W1t[off];
      w2f[ks][nt] = *(const f16x8*)&W2t[off];
    }
  float bv1[4], bv2[4];
#pragma unroll
  for (int nt = 0; nt < 4; ++nt) {
    bv1[nt] = b1[nt * 16 + l15];
    bv2[nt] = b2[nt * 16 + l15];
  }

  float s1acc[4] = {0.f, 0.f, 0.f, 0.f};
  float s2acc[4] = {0.f, 0.f, 0.f, 0.f};

#pragma unroll
  for (int tile = 0; tile < 2; ++tile) {
    int grow0 = row_base + tile * 16;
    int arow = grow0 + l15; if (arow >= N) arow = N - 1;
    const u16* grow = gh + (size_t)arow * 64;
    f16x8 a0 = *(const f16x8*)(grow + lg * 8);
    f16x8 a1 = *(const f16x8*)(grow + 32 + lg * 8);

    f32x4 c1[4];
#pragma unroll
    for (int nt = 0; nt < 4; ++nt) {
      c1[nt] = (f32x4){0.f, 0.f, 0.f, 0.f};
      c1[nt] = __builtin_amdgcn_mfma_f32_16x16x32_f16(a0, w1f[0][nt], c1[nt], 0, 0, 0);
      c1[nt] = __builtin_amdgcn_mfma_f32_16x16x32_f16(a1, w1f[1][nt], c1[nt], 0, 0, 0);
    }
#pragma unroll
    for (int nt = 0; nt < 4; ++nt)
#pragma unroll
      for (int r = 0; r < 4; ++r)
        ylds[w][lg * 4 + r][nt * 16 + l15] = f2h(fmaxf(c1[nt][r] + bv1[nt], 0.f));
    // same-wave LDS RAW: ordered by lgkmcnt, no barrier needed
    f16x8 a20 = *(const f16x8*)&ylds[w][l15][lg * 8];
    f16x8 a21 = *(const f16x8*)&ylds[w][l15][32 + lg * 8];

    f32x4 c2[4];
#pragma unroll
    for (int nt = 0; nt < 4; ++nt) {
      c2[nt] = (f32x4){0.f, 0.f, 0.f, 0.f};
      c2[nt] = __builtin_amdgcn_mfma_f32_16x16x32_f16(a20, w2f[0][nt], c2[nt], 0, 0, 0);
      c2[nt] = __builtin_amdgcn_mfma_f32_16x16x32_f16(a21, w2f[1][nt], c2[nt], 0, 0, 0);
    }
#pragma unroll
    for (int nt = 0; nt < 4; ++nt) {
#pragma unroll
      for (int r = 0; r < 4; ++r) {
        int row = grow0 + lg * 4 + r;
        float v = c2[nt][r] + bv2[nt];
        bool ok = row < N;
        if (ok) zh[(size_t)row * 64 + nt * 16 + l15] = f2h(v);
        float vm = ok ? v : 0.f;
        s1acc[nt] += vm;
        s2acc[nt] = fmaf(vm, vm, s2acc[nt]);
      }
    }
  }

#pragma unroll
  for (int nt = 0; nt < 4; ++nt) {
    float s1 = s1acc[nt], s2 = s2acc[nt];
    s1 += __shfl_xor(s1, 16, 64); s1 += __shfl_xor(s1, 32, 64);
    s2 += __shfl_xor(s2, 16, 64); s2 += __shfl_xor(s2, 32, 64);
    if (lg == 0) {
      atomicAdd(&sstat[nt * 16 + l15], s1);
      atomicAdd(&sstat[64 + nt * 16 + l15], s2);
    }
  }
  __syncthreads();
  if (tid < 128) atomicAdd(&stat[tid], sstat[tid]);
}

// ---------------- pooling (inline BN + relu) -------------------------------
__global__ __launch_bounds__(256) void pool_kernel(
    const u16* __restrict__ zh, const float* __restrict__ stat_rd,
    const float* __restrict__ gamma, const float* __restrict__ beta,
    float invN, const int* __restrict__ batch,
    float* __restrict__ sums, float* __restrict__ cnts, int N)
{
  int lane = threadIdx.x & 63;
  int wave = (blockIdx.x * blockDim.x + threadIdx.x) >> 6;
  int r0 = wave * 64;
  if (r0 >= N) return;
  float mu = stat_rd[lane] * invN;
  float var = fmaxf(stat_rd[64 + lane] * invN - mu * mu, 0.f);
  float sc = gamma[lane] * rsqrtf(var + 1e-5f);
  float sh = beta[lane] - mu * sc;
  int r1 = min(r0 + 64, N);
  int cur = batch[r0];
  float acc = 0.f;
  int cnt = 0;
  for (int r = r0; r < r1; ++r) {
    int bg = batch[r];
    if (bg != cur) {
      atomicAdd(&sums[(size_t)cur * 64 + lane], acc);
      if (lane == 0) atomicAdd(&cnts[cur], (float)cnt);
      acc = 0.f; cnt = 0; cur = bg;
    }
    acc += fmaxf(fmaf(h2f(zh[(size_t)r * 64 + lane]), sc, sh), 0.f);
    cnt++;
  }
  atomicAdd(&sums[(size_t)cur * 64 + lane], acc);
  if (lane == 0) atomicAdd(&cnts[cur], (float)cnt);
}

// ---------------- head: per-graph MLP --------------------------------------
__global__ __launch_bounds__(256) void head_kernel(
    const float* __restrict__ sums, const float* __restrict__ cnts,
    const float* __restrict__ W1, const float* __restrict__ b1,
    const float* __restrict__ W2, const float* __restrict__ b2,
    const float* __restrict__ W3, const float* __restrict__ b3,
    float* __restrict__ out)
{
  __shared__ float gf[128];
  __shared__ float h1s[256];
  __shared__ float h2s[128];
  int g = blockIdx.x, t = threadIdx.x;
  if (t < 64) {
    float sv = sums[(size_t)g * 64 + t];
    gf[t] = sv;
    gf[64 + t] = sv / fmaxf(cnts[g], 1.f);
  }
  __syncthreads();
  float a = b1[t];
  for (int k = 0; k < 128; ++k) a = fmaf(gf[k], W1[k * 256 + t], a);
  h1s[t] = fmaxf(a, 0.f);
  __syncthreads();
  if (t < 128) {
    float a2 = b2[t];
    for (int k = 0; k < 256; ++k) a2 = fmaf(h1s[k], W2[k * 128 + t], a2);
    h2s[t] = fmaxf(a2, 0.f);
  }
  __syncthreads();
  if (t == 0) {
    float s = b3[0];
    for (int k = 0; k < 128; ++k) s = fmaf(h2s[k], W3[k], s);
    out[g] = s;
  }
}

// ---------------------------------------------------------------------------
extern "C" void kernel_launch(void* const* d_in, const int* in_sizes, int n_in,
                              void* d_out, int out_size, void* d_ws, size_t ws_size,
                              hipStream_t stream)
{
  const float* x         = (const float*)d_in[0];
  const float* edge_attr = (const float*)d_in[1];
  const int*   ei        = (const int*)  d_in[2];
  const int*   batch     = (const int*)  d_in[3];
  const float* node_W    = (const float*)d_in[4];
  const float* node_b    = (const float*)d_in[5];
  const float* edge_W    = (const float*)d_in[6];
  const float* edge_b    = (const float*)d_in[7];
  const float* mlp1_W    = (const float*)d_in[8];
  const float* mlp1_b    = (const float*)d_in[9];
  const float* mlp2_W    = (const float*)d_in[10];
  const float* mlp2_b    = (const float*)d_in[11];
  const float* bn_gamma  = (const float*)d_in[12];
  const float* bn_beta   = (const float*)d_in[13];
  const float* head1_W   = (const float*)d_in[14];
  const float* head1_b   = (const float*)d_in[15];
  const float* head2_W   = (const float*)d_in[16];
  const float* head2_b   = (const float*)d_in[17];
  const float* head3_W   = (const float*)d_in[18];
  const float* head3_b   = (const float*)d_in[19];
  float* out = (float*)d_out;
  (void)n_in; (void)out_size;

  const int N = in_sizes[0] / 32;       // 100000
  const int E = in_sizes[2] / 2;        // 1600000
  const int* srcp = ei;
  const int* dstp = ei + E;

  auto al = [](size_t b) { return (b + 255) & ~(size_t)255; };
  const size_t sz_zh    = al((size_t)N * 64 * 2);   // f16 activations
  const size_t sz_g     = al((size_t)N * 64 * 2);   // f16 gather output
  const size_t sz_en    = al((size_t)E * 64 * 2);   // f16 edge encodings (nat)
  const size_t sz_pairs = al((size_t)E * 8);
  const size_t sz_pos   = al((size_t)E * 4);
  const size_t sz_rowp  = al((size_t)(N + 1) * 4);
  const size_t sz_wt    = al(32768 * 2);            // f16 transposed MLP wts
  const size_t sz_ewt   = al(2048 * 2);             // f16 padded edge wts
  const size_t sz_scr   = al((size_t)N * 4);        // deg
  const size_t sz_small = al(512) * 3 + al(NGRAPH * 64 * 4) + al(NGRAPH * 4);

  const size_t need_sorted = sz_zh + sz_g + sz_en + sz_pairs + sz_pos +
                             sz_rowp + sz_wt + sz_ewt + sz_scr + sz_small;
  const bool sorted = ws_size >= need_sorted;

  char* p = (char*)d_ws;
  auto take = [&](size_t b) -> char* { char* q = p; p += b; return q; };

  u16*   zh    = (u16*)  take(sz_zh);
  u16*   gh    = (u16*)  take(sz_g);
  int*   rowp  = (int*)  take(sz_rowp);
  u16*   Wt    = (u16*)  take(sz_wt);
  u16*   eWt   = (u16*)  take(sz_ewt);
  float* statA = (float*)take(al(512));
  float* statB = (float*)take(al(512));
  int*   bsum  = (int*)  take(al(512));
  float* sums  = (float*)take(al(NGRAPH * 64 * 4));
  float* cnts  = (float*)take(al(NGRAPH * 4));
  int*   deg   = (int*)  take(sz_scr);
  int*   pos   = (int*)  take(sz_pos);
  ix2*   pairs = (ix2*)  take(sz_pairs);

  u16* e_nat = nullptr;
  if (sorted) e_nat = (u16*)take(sz_en);

  const int NB = (N + SCAN_B - 1) / SCAN_B;
  const float invN = 1.0f / (float)N;
  float* statbuf[2] = {statA, statB};

  // ---- encoders + CSR build + weight prep ----
  hipMemsetAsync(deg, 0, (size_t)N * 4, stream);

  node_enc_kernel<<<2048, 256, 0, stream>>>(x, node_W, node_b, zh, N);
  prep_weights_kernel<<<128, 256, 0, stream>>>(mlp1_W, mlp2_W, Wt);
  prep_ew_kernel<<<8, 256, 0, stream>>>(edge_W, eWt);
  count_pos_kernel<<<(E + 255) / 256, 256, 0, stream>>>(dstp, deg, pos, E);
  scan1_kernel<<<NB, SCAN_B, 0, stream>>>(deg, rowp, bsum, N);
  scan2_kernel<<<1, 128, 0, stream>>>(bsum, NB);
  scan3_kernel<<<NB, SCAN_B, 0, stream>>>(rowp, bsum, N, E);
  if (sorted) {
    encode_mfma_kernel<<<4096, 256, 0, stream>>>(
        edge_attr, eWt, edge_b, e_nat, dstp, srcp, pos, rowp, pairs, E);
  } else {
    scatter_pairs_kernel<<<(E + 255) / 256, 256, 0, stream>>>(
        dstp, srcp, pos, rowp, pairs, E);
  }

  // ---- 4 GINE layers (2 dispatches each) ----
  const int mlpBlocks = (N + 127) / 128;
  for (int l = 0; l < 4; ++l) {
    const float* stat_rd = (l == 0) ? nullptr : statbuf[(l - 1) & 1];
    float* stat_wr = statbuf[l & 1];
    const float* gma = bn_gamma + (size_t)(l ? (l - 1) : 0) * 64;
    const float* bta = bn_beta + (size_t)(l ? (l - 1) : 0) * 64;
    if (sorted) {
      gather_kernel<<<4096, 256, 0, stream>>>(
          zh, stat_rd, gma, bta, invN, stat_wr, e_nat, pairs, rowp, gh, N);
    } else {
      gather_fallback_kernel<<<(N + 3) / 4, 256, 0, stream>>>(
          zh, stat_rd, gma, bta, invN, stat_wr, pairs, rowp,
          edge_attr, edge_W, edge_b, gh, N);
    }
    mlp_mfma_kernel<<<mlpBlocks, 256, 0, stream>>>(
        gh, zh, Wt + (size_t)l * 8192, Wt + (size_t)l * 8192 + 4096,
        mlp1_b + (size_t)l * 64, mlp2_b + (size_t)l * 64, stat_wr, N);
  }

  // ---- pooling + head ----
  hipMemsetAsync(sums, 0, (size_t)NGRAPH * 64 * 4, stream);
  hipMemsetAsync(cnts, 0, (size_t)NGRAPH * 4, stream);
  const int poolWaves = (N + 63) / 64;
  pool_kernel<<<(poolWaves + 3) / 4, 256, 0, stream>>>(
      zh, statbuf[1], bn_gamma + 3 * 64, bn_beta + 3 * 64, invN,
      batch, sums, cnts, N);
  head_kernel<<<NGRAPH, 256, 0, stream>>>(
      sums, cnts, head1_W, head1_b, head2_W, head2_b, head3_W, head3_b, out);
}

// Round 19
// 660.439 us; speedup vs baseline: 1.0492x; 1.0492x over previous
//
#include <hip/hip_runtime.h>

#define SCAN_B 1024
#define NGRAPH 128
typedef unsigned short u16;
typedef unsigned int u32;
typedef u32 u32x2 __attribute__((ext_vector_type(2)));
typedef u32 u32x4 __attribute__((ext_vector_type(4)));
typedef float fx4 __attribute__((ext_vector_type(4)));
typedef int ix2 __attribute__((ext_vector_type(2)));
typedef _Float16 f16;
typedef _Float16 f16x8 __attribute__((ext_vector_type(8)));
typedef float f32x4 __attribute__((ext_vector_type(4)));

__device__ __forceinline__ u16 f2h(float f) {
  f16 h = (f16)f;
  return __builtin_bit_cast(u16, h);
}
__device__ __forceinline__ float h2f(u16 u) {
  return (float)__builtin_bit_cast(f16, u);
}
__device__ __forceinline__ float hlo(u32 w) { return h2f((u16)(w & 0xffffu)); }
__device__ __forceinline__ float hhi(u32 w) { return h2f((u16)(w >> 16)); }

// compute BN scale/shift for 4 channels from raw stats
__device__ __forceinline__ void bn4(const float* __restrict__ stat,
                                    const float* __restrict__ gamma,
                                    const float* __restrict__ beta,
                                    float invN, int c4,
                                    float4& sc4, float4& sh4)
{
  float4 s1 = *(const float4*)&stat[c4];
  float4 s2 = *(const float4*)&stat[64 + c4];
  float4 g4 = *(const float4*)&gamma[c4];
  float4 b4 = *(const float4*)&beta[c4];
#define BN1(k)                                                        \
  { float mu = s1.k * invN;                                           \
    float var = fmaxf(s2.k * invN - mu * mu, 0.f);                    \
    sc4.k = g4.k * rsqrtf(var + 1e-5f);                               \
    sh4.k = b4.k - mu * sc4.k; }
  BN1(x) BN1(y) BN1(z) BN1(w)
#undef BN1
}

// ---------------- node encoder: h = x @ W(32x64) + b  -> f16 ---------------
__global__ __launch_bounds__(256) void node_enc_kernel(
    const float* __restrict__ x, const float* __restrict__ W,
    const float* __restrict__ b, u16* __restrict__ zh, int N)
{
  int lane = threadIdx.x & 63;
  int wave = (blockIdx.x * blockDim.x + threadIdx.x) >> 6;
  int nw = (gridDim.x * blockDim.x) >> 6;
  float wcol[32];
#pragma unroll
  for (int k = 0; k < 32; ++k) wcol[k] = W[k * 64 + lane];
  float bb = b[lane];
  for (int n = wave; n < N; n += nw) {
    const fx4* xr = (const fx4*)(x + (size_t)n * 32);
    float acc = bb;
#pragma unroll
    for (int c = 0; c < 8; ++c) {
      fx4 v = __builtin_nontemporal_load(&xr[c]);
      acc = fmaf(v[0], wcol[4 * c + 0], acc);
      acc = fmaf(v[1], wcol[4 * c + 1], acc);
      acc = fmaf(v[2], wcol[4 * c + 2], acc);
      acc = fmaf(v[3], wcol[4 * c + 3], acc);
    }
    zh[(size_t)n * 64 + lane] = f2h(acc);
  }
}

// ---------------- CSR build ------------------------------------------------
__global__ __launch_bounds__(256) void count_pos_kernel(
    const int* __restrict__ dst, int* __restrict__ deg,
    int* __restrict__ pos, int E)
{
  int e = blockIdx.x * blockDim.x + threadIdx.x;
  if (e < E) pos[e] = atomicAdd(&deg[dst[e]], 1);
}

__global__ __launch_bounds__(SCAN_B) void scan1_kernel(
    const int* __restrict__ deg, int* __restrict__ rowp,
    int* __restrict__ bsum, int N)
{
  __shared__ int s[SCAN_B];
  int tid = threadIdx.x;
  int i = blockIdx.x * SCAN_B + tid;
  int v = (i < N) ? deg[i] : 0;
  s[tid] = v;
  __syncthreads();
  for (int off = 1; off < SCAN_B; off <<= 1) {
    int t = (tid >= off) ? s[tid - off] : 0;
    __syncthreads();
    s[tid] += t;
    __syncthreads();
  }
  if (i < N) rowp[i] = s[tid] - v;          // exclusive
  if (tid == SCAN_B - 1) bsum[blockIdx.x] = s[tid];
}

__global__ __launch_bounds__(128) void scan2_kernel(int* __restrict__ bsum, int NB)
{
  __shared__ int s[128];
  int tid = threadIdx.x;
  int v = (tid < NB) ? bsum[tid] : 0;
  s[tid] = v;
  __syncthreads();
  for (int off = 1; off < 128; off <<= 1) {
    int t = (tid >= off) ? s[tid - off] : 0;
    __syncthreads();
    s[tid] += t;
    __syncthreads();
  }
  if (tid < NB) bsum[tid] = s[tid] - v;     // exclusive block offsets
}

__global__ __launch_bounds__(SCAN_B) void scan3_kernel(
    int* __restrict__ rowp, const int* __restrict__ bsum, int N, int E)
{
  int i = blockIdx.x * SCAN_B + threadIdx.x;
  if (i < N) rowp[i] += bsum[blockIdx.x];
  if (i == 0) rowp[N] = E;
}

// scattered (src,eid) pairs into CSR slots
__global__ __launch_bounds__(256) void scatter_pairs_kernel(
    const int* __restrict__ dst, const int* __restrict__ src,
    const int* __restrict__ pos, const int* __restrict__ rowp,
    ix2* __restrict__ pairs, int E)
{
  int e = blockIdx.x * blockDim.x + threadIdx.x;
  if (e >= E) return;
  int p = rowp[dst[e]] + pos[e];
  ix2 v; v[0] = src[e]; v[1] = e;
  pairs[p] = v;
}

// one-time: eWt[d][k] f16, K padded 16->32 with zeros (for MFMA B-fragments)
__global__ __launch_bounds__(256) void prep_ew_kernel(
    const float* __restrict__ eW, u16* __restrict__ eWt)
{
  int idx = blockIdx.x * 256 + threadIdx.x;   // 64*32 = 2048
  if (idx >= 2048) return;
  int d = idx >> 5, k = idx & 31;
  eWt[idx] = (k < 16) ? f2h(eW[k * 64 + d]) : (u16)0;
}

// MFMA encode: e_nat[e] = attr[e] @ eW + eb (f16, natural order)
// Per wave: 16-edge tile; LDS-transpose epilogue -> 2 coalesced 16B stores.
__global__ __launch_bounds__(256) void encode_mfma_kernel(
    const float* __restrict__ attr, const u16* __restrict__ eWt,
    const float* __restrict__ eb_, u16* __restrict__ e_nat, int E)
{
  __shared__ __align__(16) u16 ylds[4][16][72];
  int lane = threadIdx.x & 63;
  int l15 = lane & 15, lg = lane >> 4;
  int w = threadIdx.x >> 6;
  int wave = (blockIdx.x * blockDim.x + threadIdx.x) >> 6;
  int nw = (gridDim.x * blockDim.x) >> 6;

  f16x8 wf[4];
#pragma unroll
  for (int nt = 0; nt < 4; ++nt)
    wf[nt] = *(const f16x8*)&eWt[(nt * 16 + l15) * 32 + lg * 8];
  float bv[4];
#pragma unroll
  for (int nt = 0; nt < 4; ++nt) bv[nt] = eb_[nt * 16 + l15];

  int ntiles = (E + 15) >> 4;
  for (int tile = wave; tile < ntiles; tile += nw) {
    int e0 = tile << 4;
    f16x8 af = (f16x8){0, 0, 0, 0, 0, 0, 0, 0};
    if (lg < 2) {
      int e = e0 + l15; if (e >= E) e = E - 1;
      const fx4* ar = (const fx4*)(attr + (size_t)e * 16 + lg * 8);
      fx4 v0 = __builtin_nontemporal_load(ar);
      fx4 v1 = __builtin_nontemporal_load(ar + 1);
      af[0] = (f16)v0[0]; af[1] = (f16)v0[1];
      af[2] = (f16)v0[2]; af[3] = (f16)v0[3];
      af[4] = (f16)v1[0]; af[5] = (f16)v1[1];
      af[6] = (f16)v1[2]; af[7] = (f16)v1[3];
    }
    f32x4 c[4];
#pragma unroll
    for (int nt = 0; nt < 4; ++nt) {
      c[nt] = (f32x4){0.f, 0.f, 0.f, 0.f};
      c[nt] = __builtin_amdgcn_mfma_f32_16x16x32_f16(af, wf[nt], c[nt], 0, 0, 0);
    }
    // transpose through per-wave LDS (same-wave RAW: lgkmcnt-ordered)
#pragma unroll
    for (int nt = 0; nt < 4; ++nt)
#pragma unroll
      for (int r = 0; r < 4; ++r)
        ylds[w][lg * 4 + r][nt * 16 + l15] = f2h(c[nt][r] + bv[nt]);
    int e = e0 + l15;
    if (e < E) {
      u32x4 lo = *(const u32x4*)&ylds[w][l15][lg * 16];
      u32x4 hi = *(const u32x4*)&ylds[w][l15][lg * 16 + 8];
      u32x4* orow = (u32x4*)(e_nat + (size_t)e * 64 + lg * 16);
      orow[0] = lo;
      orow[1] = hi;
    }
  }
}

// ------- one-time: transpose+convert MLP weights to f16 [layer][2][d][k] ---
__global__ __launch_bounds__(256) void prep_weights_kernel(
    const float* __restrict__ mlp1_W, const float* __restrict__ mlp2_W,
    u16* __restrict__ Wt)
{
  int idx = blockIdx.x * 256 + threadIdx.x;     // 4*2*64*64 = 32768
  if (idx >= 32768) return;
  int layer = idx >> 13;
  int which = (idx >> 12) & 1;
  int d = (idx >> 6) & 63;
  int k = idx & 63;
  const float* W = which ? mlp2_W : mlp1_W;
  Wt[idx] = f2h(W[layer * 4096 + k * 64 + d]);
}

// ---------------- gather: pairs (src,eid) + natural-order e_nat ------------
// gh[i] = hval(zh[i]) + sum_{e: dst=i} relu(hval(zh[src_e]) + e_nat[eid])
__global__ __launch_bounds__(256, 4) void gather_kernel(
    const u16* __restrict__ zh, const float* __restrict__ stat_rd,
    const float* __restrict__ gamma, const float* __restrict__ beta,
    float invN, float* __restrict__ stat_wr,
    const u16* __restrict__ e_nat, const ix2* __restrict__ pairs,
    const int* __restrict__ rowp, u16* __restrict__ gh, int N)
{
  if (blockIdx.x == 0 && threadIdx.x < 128) stat_wr[threadIdx.x] = 0.f;

  int lane = threadIdx.x & 63;
  int c = lane & 15, q = lane >> 4;           // channels 4c..4c+3, quarter q
  int wave = (blockIdx.x * blockDim.x + threadIdx.x) >> 6;
  int nw = (gridDim.x * blockDim.x) >> 6;

  const bool ubn = stat_rd != nullptr;
  float4 sc4 = make_float4(1.f, 1.f, 1.f, 1.f);
  float4 sh4 = make_float4(0.f, 0.f, 0.f, 0.f);
  if (ubn) bn4(stat_rd, gamma, beta, invN, 4 * c, sc4, sh4);

  auto hval4 = [&](u32x2 z, float& h0, float& h1, float& h2, float& h3) {
    h0 = hlo(z[0]); h1 = hhi(z[0]); h2 = hlo(z[1]); h3 = hhi(z[1]);
    if (ubn) {
      h0 = fmaxf(fmaf(h0, sc4.x, sh4.x), 0.f);
      h1 = fmaxf(fmaf(h1, sc4.y, sh4.y), 0.f);
      h2 = fmaxf(fmaf(h2, sc4.z, sh4.z), 0.f);
      h3 = fmaxf(fmaf(h3, sc4.w, sh4.w), 0.f);
    }
  };
  auto body = [&](u32x2 z, u32x2 e,
                  float& A0, float& A1, float& A2, float& A3) {
    float h0, h1, h2, h3;
    hval4(z, h0, h1, h2, h3);
    A0 += fmaxf(h0 + hlo(e[0]), 0.f);
    A1 += fmaxf(h1 + hhi(e[0]), 0.f);
    A2 += fmaxf(h2 + hlo(e[1]), 0.f);
    A3 += fmaxf(h3 + hhi(e[1]), 0.f);
  };

  for (int node = wave; node < N; node += nw) {
    const int j0 = rowp[node], j1 = rowp[node + 1];
    float acc0 = 0.f, acc1 = 0.f, acc2 = 0.f, acc3 = 0.f;

    for (int base = j0; base < j1; base += 64) {
      int nb = j1 - base; if (nb > 64) nb = 64;
      ix2 iv = {0, 0};
      if (lane < nb) iv = pairs[base + lane];
      int sv = iv[0], dv = iv[1];
      int ng = nb >> 2;
      int t = 0;
      for (; t + 4 <= ng; t += 4) {           // 16 edges: loads up front
        int s0 = __shfl(sv, 4 * t + q, 64);
        int s1 = __shfl(sv, 4 * t + 4 + q, 64);
        int s2 = __shfl(sv, 4 * t + 8 + q, 64);
        int s3 = __shfl(sv, 4 * t + 12 + q, 64);
        int d0 = __shfl(dv, 4 * t + q, 64);
        int d1 = __shfl(dv, 4 * t + 4 + q, 64);
        int d2 = __shfl(dv, 4 * t + 8 + q, 64);
        int d3 = __shfl(dv, 4 * t + 12 + q, 64);
        u32x2 z0 = *(const u32x2*)(zh + (size_t)s0 * 64 + 4 * c);
        u32x2 z1 = *(const u32x2*)(zh + (size_t)s1 * 64 + 4 * c);
        u32x2 z2 = *(const u32x2*)(zh + (size_t)s2 * 64 + 4 * c);
        u32x2 z3 = *(const u32x2*)(zh + (size_t)s3 * 64 + 4 * c);
        u32x2 e0 = *(const u32x2*)(e_nat + (size_t)d0 * 64 + 4 * c);
        u32x2 e1 = *(const u32x2*)(e_nat + (size_t)d1 * 64 + 4 * c);
        u32x2 e2 = *(const u32x2*)(e_nat + (size_t)d2 * 64 + 4 * c);
        u32x2 e3 = *(const u32x2*)(e_nat + (size_t)d3 * 64 + 4 * c);
        body(z0, e0, acc0, acc1, acc2, acc3);
        body(z1, e1, acc0, acc1, acc2, acc3);
        body(z2, e2, acc0, acc1, acc2, acc3);
        body(z3, e3, acc0, acc1, acc2, acc3);
      }
      for (; t < ng; ++t) {
        int s0 = __shfl(sv, 4 * t + q, 64);
        int d0 = __shfl(dv, 4 * t + q, 64);
        u32x2 z0 = *(const u32x2*)(zh + (size_t)s0 * 64 + 4 * c);
        u32x2 e0 = *(const u32x2*)(e_nat + (size_t)d0 * 64 + 4 * c);
        body(z0, e0, acc0, acc1, acc2, acc3);
      }
      int tail = nb & 3;
      if (tail) {
        int idx = 4 * ng + (q < tail ? q : 0);  // clamp to valid slot
        int s0 = __shfl(sv, idx, 64);
        int d0 = __shfl(dv, idx, 64);
        u32x2 z0 = *(const u32x2*)(zh + (size_t)s0 * 64 + 4 * c);
        u32x2 e0 = *(const u32x2*)(e_nat + (size_t)d0 * 64 + 4 * c);
        float h0, h1, h2, h3;
        hval4(z0, h0, h1, h2, h3);
        float wmask = (q < tail) ? 1.f : 0.f;
        acc0 += wmask * fmaxf(h0 + hlo(e0[0]), 0.f);
        acc1 += wmask * fmaxf(h1 + hhi(e0[0]), 0.f);
        acc2 += wmask * fmaxf(h2 + hlo(e0[1]), 0.f);
        acc3 += wmask * fmaxf(h3 + hhi(e0[1]), 0.f);
      }
    }
    acc0 += __shfl_xor(acc0, 16, 64); acc0 += __shfl_xor(acc0, 32, 64);
    acc1 += __shfl_xor(acc1, 16, 64); acc1 += __shfl_xor(acc1, 32, 64);
    acc2 += __shfl_xor(acc2, 16, 64); acc2 += __shfl_xor(acc2, 32, 64);
    acc3 += __shfl_xor(acc3, 16, 64); acc3 += __shfl_xor(acc3, 32, 64);
    if (q == 0) {
      u32x2 zn = *(const u32x2*)(zh + (size_t)node * 64 + 4 * c);
      float h0, h1, h2, h3;
      hval4(zn, h0, h1, h2, h3);
      acc0 += h0; acc1 += h1; acc2 += h2; acc3 += h3;
      u32x2 o;
      o[0] = (u32)f2h(acc0) | ((u32)f2h(acc1) << 16);
      o[1] = (u32)f2h(acc2) | ((u32)f2h(acc3) << 16);
      *(u32x2*)(gh + (size_t)node * 64 + 4 * c) = o;
    }
  }
}

// ---------------- fallback gather (pairs + f32 attr recompute) -------------
__global__ __launch_bounds__(256) void gather_fallback_kernel(
    const u16* __restrict__ zh, const float* __restrict__ stat_rd,
    const float* __restrict__ gamma, const float* __restrict__ beta,
    float invN, float* __restrict__ stat_wr,
    const ix2* __restrict__ pairs, const int* __restrict__ rowp,
    const float* __restrict__ attr, const float* __restrict__ eW,
    const float* __restrict__ eb_, u16* __restrict__ gh, int N)
{
  if (blockIdx.x == 0 && threadIdx.x < 128) stat_wr[threadIdx.x] = 0.f;
  int lane = threadIdx.x & 63;
  int node = (blockIdx.x * blockDim.x + threadIdx.x) >> 6;
  if (node >= N) return;
  const bool ubn = stat_rd != nullptr;
  float sc = 1.f, sh = 0.f;
  if (ubn) {
    float mu = stat_rd[lane] * invN;
    float var = fmaxf(stat_rd[64 + lane] * invN - mu * mu, 0.f);
    sc = gamma[lane] * rsqrtf(var + 1e-5f);
    sh = beta[lane] - mu * sc;
  }
  auto hval = [&](float zz) -> float {
    float v = fmaf(zz, sc, sh);
    return ubn ? fmaxf(v, 0.f) : v;
  };
  float wcol[16];
#pragma unroll
  for (int k = 0; k < 16; ++k) wcol[k] = eW[k * 64 + lane];
  float eb = eb_[lane];
  const int j0 = rowp[node], j1 = rowp[node + 1];
  float acc = hval(h2f(zh[(size_t)node * 64 + lane]));
  for (int j = j0; j < j1; ++j) {
    ix2 pr = pairs[j];
    int s = pr[0], eid = pr[1];
    const float4* ar = (const float4*)(attr + (size_t)eid * 16);
    float4 a0 = ar[0], a1 = ar[1], a2 = ar[2], a3 = ar[3];
    float m = eb;
    m = fmaf(a0.x, wcol[0], m);  m = fmaf(a0.y, wcol[1], m);
    m = fmaf(a0.z, wcol[2], m);  m = fmaf(a0.w, wcol[3], m);
    m = fmaf(a1.x, wcol[4], m);  m = fmaf(a1.y, wcol[5], m);
    m = fmaf(a1.z, wcol[6], m);  m = fmaf(a1.w, wcol[7], m);
    m = fmaf(a2.x, wcol[8], m);  m = fmaf(a2.y, wcol[9], m);
    m = fmaf(a2.z, wcol[10], m); m = fmaf(a2.w, wcol[11], m);
    m = fmaf(a3.x, wcol[12], m); m = fmaf(a3.y, wcol[13], m);
    m = fmaf(a3.z, wcol[14], m); m = fmaf(a3.w, wcol[15], m);
    acc += fmaxf(hval(h2f(zh[(size_t)s * 64 + lane])) + m, 0.f);
  }
  gh[(size_t)node * 64 + lane] = f2h(acc);
}

// ---------------- MFMA fused MLP + BN stats (32 rows/wave) -----------------
__global__ __launch_bounds__(256) void mlp_mfma_kernel(
    const u16* __restrict__ gh, u16* __restrict__ zh,
    const u16* __restrict__ W1t, const u16* __restrict__ W2t,
    const float* __restrict__ b1, const float* __restrict__ b2,
    float* __restrict__ stat, int N)
{
  __shared__ __align__(16) u16 ylds[4][16][72];
  __shared__ float sstat[128];
  int tid = threadIdx.x, lane = tid & 63, w = tid >> 6;
  int l15 = lane & 15, lg = lane >> 4;
  int row_base = (blockIdx.x * 4 + w) * 32;

  if (tid < 128) sstat[tid] = 0.f;
  __syncthreads();

  f16x8 w1f[2][4], w2f[2][4];
#pragma unroll
  for (int ks = 0; ks < 2; ++ks)
#pragma unroll
    for (int nt = 0; nt < 4; ++nt) {
      int off = (nt * 16 + l15) * 64 + ks * 32 + lg * 8;
      w1f[ks][nt] = *(const f16x8*)&W1t[off];
      w2f[ks][nt] = *(const f16x8*)&W2t[off];
    }
  float bv1[4], bv2[4];
#pragma unroll
  for (int nt = 0; nt < 4; ++nt) {
    bv1[nt] = b1[nt * 16 + l15];
    bv2[nt] = b2[nt * 16 + l15];
  }

  float s1acc[4] = {0.f, 0.f, 0.f, 0.f};
  float s2acc[4] = {0.f, 0.f, 0.f, 0.f};

#pragma unroll
  for (int tile = 0; tile < 2; ++tile) {
    int grow0 = row_base + tile * 16;
    int arow = grow0 + l15; if (arow >= N) arow = N - 1;
    const u16* grow = gh + (size_t)arow * 64;
    f16x8 a0 = *(const f16x8*)(grow + lg * 8);
    f16x8 a1 = *(const f16x8*)(grow + 32 + lg * 8);

    f32x4 c1[4];
#pragma unroll
    for (int nt = 0; nt < 4; ++nt) {
      c1[nt] = (f32x4){0.f, 0.f, 0.f, 0.f};
      c1[nt] = __builtin_amdgcn_mfma_f32_16x16x32_f16(a0, w1f[0][nt], c1[nt], 0, 0, 0);
      c1[nt] = __builtin_amdgcn_mfma_f32_16x16x32_f16(a1, w1f[1][nt], c1[nt], 0, 0, 0);
    }
#pragma unroll
    for (int nt = 0; nt < 4; ++nt)
#pragma unroll
      for (int r = 0; r < 4; ++r)
        ylds[w][lg * 4 + r][nt * 16 + l15] = f2h(fmaxf(c1[nt][r] + bv1[nt], 0.f));
    // same-wave LDS RAW: ordered by lgkmcnt, no barrier needed
    f16x8 a20 = *(const f16x8*)&ylds[w][l15][lg * 8];
    f16x8 a21 = *(const f16x8*)&ylds[w][l15][32 + lg * 8];

    f32x4 c2[4];
#pragma unroll
    for (int nt = 0; nt < 4; ++nt) {
      c2[nt] = (f32x4){0.f, 0.f, 0.f, 0.f};
      c2[nt] = __builtin_amdgcn_mfma_f32_16x16x32_f16(a20, w2f[0][nt], c2[nt], 0, 0, 0);
      c2[nt] = __builtin_amdgcn_mfma_f32_16x16x32_f16(a21, w2f[1][nt], c2[nt], 0, 0, 0);
    }
#pragma unroll
    for (int nt = 0; nt < 4; ++nt) {
#pragma unroll
      for (int r = 0; r < 4; ++r) {
        int row = grow0 + lg * 4 + r;
        float v = c2[nt][r] + bv2[nt];
        bool ok = row < N;
        if (ok) zh[(size_t)row * 64 + nt * 16 + l15] = f2h(v);
        float vm = ok ? v : 0.f;
        s1acc[nt] += vm;
        s2acc[nt] = fmaf(vm, vm, s2acc[nt]);
      }
    }
  }

#pragma unroll
  for (int nt = 0; nt < 4; ++nt) {
    float s1 = s1acc[nt], s2 = s2acc[nt];
    s1 += __shfl_xor(s1, 16, 64); s1 += __shfl_xor(s1, 32, 64);
    s2 += __shfl_xor(s2, 16, 64); s2 += __shfl_xor(s2, 32, 64);
    if (lg == 0) {
      atomicAdd(&sstat[nt * 16 + l15], s1);
      atomicAdd(&sstat[64 + nt * 16 + l15], s2);
    }
  }
  __syncthreads();
  if (tid < 128) atomicAdd(&stat[tid], sstat[tid]);
}

// ---------------- pooling (inline BN + relu) -------------------------------
__global__ __launch_bounds__(256) void pool_kernel(
    const u16* __restrict__ zh, const float* __restrict__ stat_rd,
    const float* __restrict__ gamma, const float* __restrict__ beta,
    float invN, const int* __restrict__ batch,
    float* __restrict__ sums, float* __restrict__ cnts, int N)
{
  int lane = threadIdx.x & 63;
  int wave = (blockIdx.x * blockDim.x + threadIdx.x) >> 6;
  int r0 = wave * 64;
  if (r0 >= N) return;
  float mu = stat_rd[lane] * invN;
  float var = fmaxf(stat_rd[64 + lane] * invN - mu * mu, 0.f);
  float sc = gamma[lane] * rsqrtf(var + 1e-5f);
  float sh = beta[lane] - mu * sc;
  int r1 = min(r0 + 64, N);
  int cur = batch[r0];
  float acc = 0.f;
  int cnt = 0;
  for (int r = r0; r < r1; ++r) {
    int bg = batch[r];
    if (bg != cur) {
      atomicAdd(&sums[(size_t)cur * 64 + lane], acc);
      if (lane == 0) atomicAdd(&cnts[cur], (float)cnt);
      acc = 0.f; cnt = 0; cur = bg;
    }
    acc += fmaxf(fmaf(h2f(zh[(size_t)r * 64 + lane]), sc, sh), 0.f);
    cnt++;
  }
  atomicAdd(&sums[(size_t)cur * 64 + lane], acc);
  if (lane == 0) atomicAdd(&cnts[cur], (float)cnt);
}

// ---------------- head: per-graph MLP --------------------------------------
__global__ __launch_bounds__(256) void head_kernel(
    const float* __restrict__ sums, const float* __restrict__ cnts,
    const float* __restrict__ W1, const float* __restrict__ b1,
    const float* __restrict__ W2, const float* __restrict__ b2,
    const float* __restrict__ W3, const float* __restrict__ b3,
    float* __restrict__ out)
{
  __shared__ float gf[128];
  __shared__ float h1s[256];
  __shared__ float h2s[128];
  int g = blockIdx.x, t = threadIdx.x;
  if (t < 64) {
    float sv = sums[(size_t)g * 64 + t];
    gf[t] = sv;
    gf[64 + t] = sv / fmaxf(cnts[g], 1.f);
  }
  __syncthreads();
  float a = b1[t];
  for (int k = 0; k < 128; ++k) a = fmaf(gf[k], W1[k * 256 + t], a);
  h1s[t] = fmaxf(a, 0.f);
  __syncthreads();
  if (t < 128) {
    float a2 = b2[t];
    for (int k = 0; k < 256; ++k) a2 = fmaf(h1s[k], W2[k * 128 + t], a2);
    h2s[t] = fmaxf(a2, 0.f);
  }
  __syncthreads();
  if (t == 0) {
    float s = b3[0];
    for (int k = 0; k < 128; ++k) s = fmaf(h2s[k], W3[k], s);
    out[g] = s;
  }
}

// ---------------------------------------------------------------------------
extern "C" void kernel_launch(void* const* d_in, const int* in_sizes, int n_in,
                              void* d_out, int out_size, void* d_ws, size_t ws_size,
                              hipStream_t stream)
{
  const float* x         = (const float*)d_in[0];
  const float* edge_attr = (const float*)d_in[1];
  const int*   ei        = (const int*)  d_in[2];
  const int*   batch     = (const int*)  d_in[3];
  const float* node_W    = (const float*)d_in[4];
  const float* node_b    = (const float*)d_in[5];
  const float* edge_W    = (const float*)d_in[6];
  const float* edge_b    = (const float*)d_in[7];
  const float* mlp1_W    = (const float*)d_in[8];
  const float* mlp1_b    = (const float*)d_in[9];
  const float* mlp2_W    = (const float*)d_in[10];
  const float* mlp2_b    = (const float*)d_in[11];
  const float* bn_gamma  = (const float*)d_in[12];
  const float* bn_beta   = (const float*)d_in[13];
  const float* head1_W   = (const float*)d_in[14];
  const float* head1_b   = (const float*)d_in[15];
  const float* head2_W   = (const float*)d_in[16];
  const float* head2_b   = (const float*)d_in[17];
  const float* head3_W   = (const float*)d_in[18];
  const float* head3_b   = (const float*)d_in[19];
  float* out = (float*)d_out;
  (void)n_in; (void)out_size;

  const int N = in_sizes[0] / 32;       // 100000
  const int E = in_sizes[2] / 2;        // 1600000
  const int* srcp = ei;
  const int* dstp = ei + E;

  auto al = [](size_t b) { return (b + 255) & ~(size_t)255; };
  const size_t sz_zh    = al((size_t)N * 64 * 2);   // f16 activations
  const size_t sz_g     = al((size_t)N * 64 * 2);   // f16 gather output
  const size_t sz_en    = al((size_t)E * 64 * 2);   // f16 edge encodings (nat)
  const size_t sz_pairs = al((size_t)E * 8);
  const size_t sz_pos   = al((size_t)E * 4);
  const size_t sz_rowp  = al((size_t)(N + 1) * 4);
  const size_t sz_wt    = al(32768 * 2);            // f16 transposed MLP wts
  const size_t sz_ewt   = al(2048 * 2);             // f16 padded edge wts
  const size_t sz_scr   = al((size_t)N * 4);        // deg
  const size_t sz_small = al(512) * 3 + al(NGRAPH * 64 * 4) + al(NGRAPH * 4);

  const size_t need_sorted = sz_zh + sz_g + sz_en + sz_pairs + sz_pos +
                             sz_rowp + sz_wt + sz_ewt + sz_scr + sz_small;
  const bool sorted = ws_size >= need_sorted;

  char* p = (char*)d_ws;
  auto take = [&](size_t b) -> char* { char* q = p; p += b; return q; };

  u16*   zh    = (u16*)  take(sz_zh);
  u16*   gh    = (u16*)  take(sz_g);
  int*   rowp  = (int*)  take(sz_rowp);
  u16*   Wt    = (u16*)  take(sz_wt);
  u16*   eWt   = (u16*)  take(sz_ewt);
  float* statA = (float*)take(al(512));
  float* statB = (float*)take(al(512));
  int*   bsum  = (int*)  take(al(512));
  float* sums  = (float*)take(al(NGRAPH * 64 * 4));
  float* cnts  = (float*)take(al(NGRAPH * 4));
  int*   deg   = (int*)  take(sz_scr);
  int*   pos   = (int*)  take(sz_pos);
  ix2*   pairs = (ix2*)  take(sz_pairs);

  u16* e_nat = nullptr;
  if (sorted) e_nat = (u16*)take(sz_en);

  const int NB = (N + SCAN_B - 1) / SCAN_B;
  const float invN = 1.0f / (float)N;
  float* statbuf[2] = {statA, statB};

  // ---- encoders + CSR build + weight prep ----
  hipMemsetAsync(deg, 0, (size_t)N * 4, stream);

  node_enc_kernel<<<2048, 256, 0, stream>>>(x, node_W, node_b, zh, N);
  prep_weights_kernel<<<128, 256, 0, stream>>>(mlp1_W, mlp2_W, Wt);
  prep_ew_kernel<<<8, 256, 0, stream>>>(edge_W, eWt);
  count_pos_kernel<<<(E + 255) / 256, 256, 0, stream>>>(dstp, deg, pos, E);
  scan1_kernel<<<NB, SCAN_B, 0, stream>>>(deg, rowp, bsum, N);
  scan2_kernel<<<1, 128, 0, stream>>>(bsum, NB);
  scan3_kernel<<<NB, SCAN_B, 0, stream>>>(rowp, bsum, N, E);
  scatter_pairs_kernel<<<(E + 255) / 256, 256, 0, stream>>>(
      dstp, srcp, pos, rowp, pairs, E);
  if (sorted) {
    encode_mfma_kernel<<<4096, 256, 0, stream>>>(
        edge_attr, eWt, edge_b, e_nat, E);
  }

  // ---- 4 GINE layers (2 dispatches each) ----
  const int mlpBlocks = (N + 127) / 128;
  for (int l = 0; l < 4; ++l) {
    const float* stat_rd = (l == 0) ? nullptr : statbuf[(l - 1) & 1];
    float* stat_wr = statbuf[l & 1];
    const float* gma = bn_gamma + (size_t)(l ? (l - 1) : 0) * 64;
    const float* bta = bn_beta + (size_t)(l ? (l - 1) : 0) * 64;
    if (sorted) {
      gather_kernel<<<4096, 256, 0, stream>>>(
          zh, stat_rd, gma, bta, invN, stat_wr, e_nat, pairs, rowp, gh, N);
    } else {
      gather_fallback_kernel<<<(N + 3) / 4, 256, 0, stream>>>(
          zh, stat_rd, gma, bta, invN, stat_wr, pairs, rowp,
          edge_attr, edge_W, edge_b, gh, N);
    }
    mlp_mfma_kernel<<<mlpBlocks, 256, 0, stream>>>(
        gh, zh, Wt + (size_t)l * 8192, Wt + (size_t)l * 8192 + 4096,
        mlp1_b + (size_t)l * 64, mlp2_b + (size_t)l * 64, stat_wr, N);
  }

  // ---- pooling + head ----
  hipMemsetAsync(sums, 0, (size_t)NGRAPH * 64 * 4, stream);
  hipMemsetAsync(cnts, 0, (size_t)NGRAPH * 4, stream);
  const int poolWaves = (N + 63) / 64;
  pool_kernel<<<(poolWaves + 3) / 4, 256, 0, stream>>>(
      zh, statbuf[1], bn_gamma + 3 * 64, bn_beta + 3 * 64, invN,
      batch, sums, cnts, N);
  head_kernel<<<NGRAPH, 256, 0, stream>>>(
      sums, cnts, head1_W, head1_b, head2_W, head2_b, head3_W, head3_b, out);
}